// Round 1
// baseline (559.902 us; speedup 1.0000x reference)
//
#include <hip/hip_runtime.h>
#include <hip/hip_bf16.h>
#include <stdint.h>

#define SEQ     4096
#define NBATCH  16
#define DMODEL  768
#define NHEAD   12
#define HDIM    64
#define WINSZ   64
#define SHIFT_T 32
#define QKV_N   (3*DMODEL)   // 2304

typedef __attribute__((ext_vector_type(8))) short  bf16x8;
typedef __attribute__((ext_vector_type(4))) float  f32x4;

static __device__ __forceinline__ unsigned short f2bf(float f) {
  union { float f; unsigned u; } v; v.f = f;
  unsigned r = v.u + 0x7fffu + ((v.u >> 16) & 1u);
  return (unsigned short)(r >> 16);
}

// ---- cast x (fp32) -> bf16 with +SHIFT roll fused; chunked by token base c0
__global__ void k_cvt_x(const float* __restrict__ x, unsigned short* __restrict__ xb,
                        long long c0, long long n8) {
  for (long long i = (long long)blockIdx.x*blockDim.x + threadIdx.x; i < n8;
       i += (long long)gridDim.x*blockDim.x) {
    long long e = i*8;
    int d = (int)(e % DMODEL);
    long long gt = c0 + e / DMODEL;          // global rolled token index
    int t = (int)(gt & (SEQ-1));
    long long b = gt >> 12;
    int ts = (t - SHIFT_T) & (SEQ-1);        // source (unrolled) position
    const float* src = x + (((b << 12) + ts) * (long long)DMODEL + d);
    float4 a0 = *(const float4*)src;
    float4 a1 = *(const float4*)(src + 4);
    bf16x8 o;
    o[0]=(short)f2bf(a0.x); o[1]=(short)f2bf(a0.y); o[2]=(short)f2bf(a0.z); o[3]=(short)f2bf(a0.w);
    o[4]=(short)f2bf(a1.x); o[5]=(short)f2bf(a1.y); o[6]=(short)f2bf(a1.z); o[7]=(short)f2bf(a1.w);
    *(bf16x8*)(xb + e) = o;
  }
}

// ---- generic fp32 -> bf16 (weights)
__global__ void k_cvt_w(const float* __restrict__ w, unsigned short* __restrict__ wb, int n8) {
  int i = blockIdx.x*blockDim.x + threadIdx.x;
  if (i >= n8) return;
  float4 a0 = ((const float4*)w)[2*i];
  float4 a1 = ((const float4*)w)[2*i+1];
  bf16x8 o;
  o[0]=(short)f2bf(a0.x); o[1]=(short)f2bf(a0.y); o[2]=(short)f2bf(a0.z); o[3]=(short)f2bf(a0.w);
  o[4]=(short)f2bf(a1.x); o[5]=(short)f2bf(a1.y); o[6]=(short)f2bf(a1.z); o[7]=(short)f2bf(a1.w);
  ((bf16x8*)wb)[i] = o;
}

// ---- 128x128 bf16 GEMM, C[m,n] = sum_k A[m,k]*B[n,k] + bias[n]
// MODE 0: write bf16 into Cb.  MODE 1: write fp32 into Cf with -SHIFT roll scatter.
template<int MODE>
__global__ __launch_bounds__(256, 2)
void k_gemm_bt(const unsigned short* __restrict__ A, const unsigned short* __restrict__ Bw,
               const float* __restrict__ bias, unsigned short* __restrict__ Cb,
               float* __restrict__ Cf, int M, int N, int K, int nTN, long long c0) {
  __shared__ char sA[128*128];   // 128 rows x 64 bf16 (128B/row)
  __shared__ char sB[128*128];
  int nwg = gridDim.x;           // divisible by 8 by construction
  int cpx = nwg >> 3;
  int wg  = (blockIdx.x & 7) * cpx + (blockIdx.x >> 3);   // XCD-contiguous
  int bm = wg / nTN, bn = wg % nTN;
  long long m0 = (long long)bm * 128;
  int n0 = bn * 128;
  int lane = threadIdx.x & 63, wid = threadIdx.x >> 6;
  int wr = wid >> 1, wc = wid & 1;            // 2x2 waves, 64x64 each
  int l8 = lane >> 3, lc = lane & 7;

  f32x4 acc[4][4];
  #pragma unroll
  for (int i = 0; i < 4; ++i)
    #pragma unroll
    for (int j = 0; j < 4; ++j) acc[i][j] = (f32x4){0.f,0.f,0.f,0.f};

  for (int kt = 0; kt < K; kt += 64) {
    __syncthreads();   // previous tile fully consumed
    #pragma unroll
    for (int i = 0; i < 4; ++i) {
      int r   = i*4 + wid;               // 16 regions of 8 rows
      int row = r*8 + l8;
      int ch  = lc ^ (row & 7);          // inverse-swizzled global source (rule #21)
      const unsigned short* ga = A  + (m0 + row) * (long long)K + kt + ch*8;
      const unsigned short* gb = Bw + (long long)(n0 + row) * K + kt + ch*8;
      __builtin_amdgcn_global_load_lds((const __attribute__((address_space(1))) unsigned int*)(const void*)ga,
          (__attribute__((address_space(3))) unsigned int*)(void*)(sA + r*1024), 16, 0, 0);
      __builtin_amdgcn_global_load_lds((const __attribute__((address_space(1))) unsigned int*)(const void*)gb,
          (__attribute__((address_space(3))) unsigned int*)(void*)(sB + r*1024), 16, 0, 0);
    }
    __syncthreads();   // drains vmcnt(0): tile resident
    #pragma unroll
    for (int kk = 0; kk < 2; ++kk) {
      bf16x8 af[4], bf[4];
      #pragma unroll
      for (int mf = 0; mf < 4; ++mf) {
        int row = wr*64 + mf*16 + (lane & 15);
        int p = row*128 + (kk*32 + (lane >> 4)*8)*2;
        af[mf] = *(const bf16x8*)(sA + (p ^ ((row & 7) << 4)));   // swizzled read
      }
      #pragma unroll
      for (int nf = 0; nf < 4; ++nf) {
        int row = wc*64 + nf*16 + (lane & 15);
        int p = row*128 + (kk*32 + (lane >> 4)*8)*2;
        bf[nf] = *(const bf16x8*)(sB + (p ^ ((row & 7) << 4)));
      }
      #pragma unroll
      for (int mf = 0; mf < 4; ++mf)
        #pragma unroll
        for (int nf = 0; nf < 4; ++nf)
          acc[mf][nf] = __builtin_amdgcn_mfma_f32_16x16x32_bf16(af[mf], bf[nf], acc[mf][nf], 0, 0, 0);
    }
  }

  int cl = lane & 15, g4 = lane >> 4;
  #pragma unroll
  for (int mf = 0; mf < 4; ++mf) {
    #pragma unroll
    for (int nf = 0; nf < 4; ++nf) {
      int n = n0 + wc*64 + nf*16 + cl;
      float bv = bias[n];
      #pragma unroll
      for (int r = 0; r < 4; ++r) {
        long long m = m0 + wr*64 + mf*16 + g4*4 + r;
        float v = acc[mf][nf][r] + bv;
        if (MODE == 0) {
          Cb[m * (long long)N + n] = f2bf(v);
        } else {
          long long gm = c0 + m;                                     // global rolled token
          long long om = (gm & ~(long long)(SEQ-1)) | ((gm - SHIFT_T) & (long long)(SEQ-1));
          Cf[om * (long long)N + n] = v;
        }
      }
    }
  }
}

// ---- per-(window,head) attention: S = QK^T*scale + rel_bias, softmax, O = P V
__global__ __launch_bounds__(256, 4)
void k_attn(const unsigned short* __restrict__ qkv, const float* __restrict__ rel_bias,
            unsigned short* __restrict__ y) {
  int w = blockIdx.x / NHEAD;
  int h = blockIdx.x - w*NHEAD;
  __shared__ unsigned short sQ[64*72], sK[64*72], sV[64*72];
  __shared__ unsigned short sP[4][16*72];
  __shared__ float rb[128];
  int tid = threadIdx.x, lane = tid & 63, wid = tid >> 6;
  int cl = lane & 15, g4 = lane >> 4;

  if (tid < 2*WINSZ - 1) rb[tid] = rel_bias[h*(2*WINSZ-1) + tid];

  const unsigned short* base = qkv + (long long)w*WINSZ*QKV_N + h*HDIM;
  #pragma unroll
  for (int pass = 0; pass < 2; ++pass) {
    int row = (tid >> 3) + pass*32;
    int ch  = tid & 7;
    const unsigned short* src = base + (long long)row*QKV_N + ch*8;
    *(bf16x8*)(sQ + row*72 + ch*8) = *(const bf16x8*)(src);
    *(bf16x8*)(sK + row*72 + ch*8) = *(const bf16x8*)(src + DMODEL);
    *(bf16x8*)(sV + row*72 + ch*8) = *(const bf16x8*)(src + 2*DMODEL);
  }
  __syncthreads();

  // QK^T : wave wid owns q-rows [wid*16, wid*16+16)
  f32x4 sc[4];
  #pragma unroll
  for (int nt = 0; nt < 4; ++nt) sc[nt] = (f32x4){0.f,0.f,0.f,0.f};
  #pragma unroll
  for (int kk = 0; kk < 2; ++kk) {
    bf16x8 aq = *(const bf16x8*)(sQ + (wid*16 + cl)*72 + kk*32 + g4*8);
    #pragma unroll
    for (int nt = 0; nt < 4; ++nt) {
      bf16x8 bk = *(const bf16x8*)(sK + (nt*16 + cl)*72 + kk*32 + g4*8);
      sc[nt] = __builtin_amdgcn_mfma_f32_16x16x32_bf16(aq, bk, sc[nt], 0, 0, 0);
    }
  }

  // softmax over 64 cols; C layout: col = nt*16+cl, row(within wave) = g4*4 + r
  float pv[4][4];
  #pragma unroll
  for (int r = 0; r < 4; ++r) {
    int qi = wid*16 + g4*4 + r;
    float mx = -1e30f;
    #pragma unroll
    for (int nt = 0; nt < 4; ++nt) {
      int kj = nt*16 + cl;
      float v = sc[nt][r]*0.125f + rb[kj - qi + (WINSZ-1)];
      pv[nt][r] = v;
      mx = fmaxf(mx, v);
    }
    #pragma unroll
    for (int m = 1; m < 16; m <<= 1) mx = fmaxf(mx, __shfl_xor(mx, m, 64));
    float sum = 0.f;
    #pragma unroll
    for (int nt = 0; nt < 4; ++nt) { float e = __expf(pv[nt][r]-mx); pv[nt][r] = e; sum += e; }
    #pragma unroll
    for (int m = 1; m < 16; m <<= 1) sum += __shfl_xor(sum, m, 64);
    float inv = 1.f / sum;
    #pragma unroll
    for (int nt = 0; nt < 4; ++nt)
      sP[wid][(g4*4+r)*72 + nt*16 + cl] = f2bf(pv[nt][r]*inv);
  }
  // wave-local LDS RAW: compiler inserts lgkmcnt; sP[wid] is wave-private

  // O = P @ V
  f32x4 o[4];
  #pragma unroll
  for (int nt = 0; nt < 4; ++nt) o[nt] = (f32x4){0.f,0.f,0.f,0.f};
  #pragma unroll
  for (int kk = 0; kk < 2; ++kk) {
    bf16x8 ap = *(const bf16x8*)(&sP[wid][cl*72 + kk*32 + g4*8]);
    #pragma unroll
    for (int nt = 0; nt < 4; ++nt) {
      bf16x8 bv;
      #pragma unroll
      for (int j = 0; j < 8; ++j)
        bv[j] = (short)sV[(kk*32 + g4*8 + j)*72 + nt*16 + cl];   // column gather of V
      o[nt] = __builtin_amdgcn_mfma_f32_16x16x32_bf16(ap, bv, o[nt], 0, 0, 0);
    }
  }

  long long tokbase = (long long)w * WINSZ;
  #pragma unroll
  for (int nt = 0; nt < 4; ++nt)
    #pragma unroll
    for (int r = 0; r < 4; ++r) {
      int row = wid*16 + g4*4 + r;
      y[(tokbase + row) * (long long)DMODEL + h*HDIM + nt*16 + cl] = f2bf(o[nt][r]);
    }
}

extern "C" void kernel_launch(void* const* d_in, const int* in_sizes, int n_in,
                              void* d_out, int out_size, void* d_ws, size_t ws_size,
                              hipStream_t stream) {
  const float* x      = (const float*)d_in[0];
  const float* qkv_w  = (const float*)d_in[1];
  const float* qkv_b  = (const float*)d_in[2];
  const float* proj_w = (const float*)d_in[3];
  const float* proj_b = (const float*)d_in[4];
  const float* rel_b  = (const float*)d_in[5];
  float* out = (float*)d_out;

  const long long NTOK = (long long)NBATCH * SEQ;    // 65536
  const size_t wbytes = (size_t)QKV_N*DMODEL*2 + (size_t)DMODEL*DMODEL*2;  // 4,718,592

  // pick chunk count: smallest C in {1,2,4,8,16} whose working set fits ws
  int C = 16;
  for (int c : {1, 2, 4, 8, 16}) {
    size_t tpc = (size_t)NTOK / c;
    size_t need = tpc*QKV_N*2 + tpc*DMODEL*2 + wbytes;
    if (need <= ws_size) { C = c; break; }
  }
  long long tpc = NTOK / C;

  char* ws = (char*)d_ws;
  unsigned short* qkvb = (unsigned short*)ws;                               // tpc*2304 bf16
  unsigned short* xb   = (unsigned short*)(ws + (size_t)tpc*QKV_N*2);       // tpc*768 bf16 (aliased as y)
  unsigned short* wq   = (unsigned short*)(ws + (size_t)tpc*QKV_N*2 + (size_t)tpc*DMODEL*2);
  unsigned short* wp   = wq + (size_t)QKV_N*DMODEL;

  k_cvt_w<<<(QKV_N*DMODEL/8 + 255)/256, 256, 0, stream>>>(qkv_w, wq, QKV_N*DMODEL/8);
  k_cvt_w<<<(DMODEL*DMODEL/8 + 255)/256, 256, 0, stream>>>(proj_w, wp, DMODEL*DMODEL/8);

  for (int c = 0; c < C; ++c) {
    long long c0 = (long long)c * tpc;
    long long n8 = tpc * DMODEL / 8;
    int cvtGrid = (int)((n8 + 255) / 256); if (cvtGrid > 2048) cvtGrid = 2048;
    k_cvt_x<<<cvtGrid, 256, 0, stream>>>(x, xb, c0, n8);

    int mT = (int)(tpc / 128);
    k_gemm_bt<0><<<mT * (QKV_N/128), 256, 0, stream>>>(xb, wq, qkv_b, qkvb, nullptr,
                                                       (int)tpc, QKV_N, DMODEL, QKV_N/128, c0);
    k_attn<<<(int)(tpc/WINSZ) * NHEAD, 256, 0, stream>>>(qkvb, rel_b, xb /*reuse as y*/);
    k_gemm_bt<1><<<mT * (DMODEL/128), 256, 0, stream>>>(xb, wp, proj_b, nullptr, out,
                                                        (int)tpc, DMODEL, DMODEL, DMODEL/128, c0);
  }
}

// Round 2
// 534.366 us; speedup vs baseline: 1.0478x; 1.0478x over previous
//
#include <hip/hip_runtime.h>
#include <hip/hip_bf16.h>
#include <stdint.h>

#define SEQ     4096
#define NBATCH  16
#define DMODEL  768
#define NHEAD   12
#define HDIM    64
#define WINSZ   64
#define SHIFT_T 32
#define QKV_N   (3*DMODEL)   // 2304

typedef __attribute__((ext_vector_type(8))) short  bf16x8;
typedef __attribute__((ext_vector_type(4))) float  f32x4;

static __device__ __forceinline__ unsigned short f2bf(float f) {
  union { float f; unsigned u; } v; v.f = f;
  unsigned r = v.u + 0x7fffu + ((v.u >> 16) & 1u);
  return (unsigned short)(r >> 16);
}

#define G2L(gp, lp) __builtin_amdgcn_global_load_lds( \
    (const __attribute__((address_space(1))) unsigned*)(const void*)(gp), \
    (__attribute__((address_space(3))) unsigned*)(void*)(lp), 16, 0, 0)

// ---- cast x (fp32) -> bf16 with +SHIFT roll fused; chunked by token base c0
__global__ void k_cvt_x(const float* __restrict__ x, unsigned short* __restrict__ xb,
                        long long c0, long long n8) {
  for (long long i = (long long)blockIdx.x*blockDim.x + threadIdx.x; i < n8;
       i += (long long)gridDim.x*blockDim.x) {
    long long e = i*8;
    int d = (int)(e % DMODEL);
    long long gt = c0 + e / DMODEL;          // global rolled token index
    int t = (int)(gt & (SEQ-1));
    long long b = gt >> 12;
    int ts = (t - SHIFT_T) & (SEQ-1);        // source (unrolled) position
    const float* src = x + (((b << 12) + ts) * (long long)DMODEL + d);
    float4 a0 = *(const float4*)src;
    float4 a1 = *(const float4*)(src + 4);
    bf16x8 o;
    o[0]=(short)f2bf(a0.x); o[1]=(short)f2bf(a0.y); o[2]=(short)f2bf(a0.z); o[3]=(short)f2bf(a0.w);
    o[4]=(short)f2bf(a1.x); o[5]=(short)f2bf(a1.y); o[6]=(short)f2bf(a1.z); o[7]=(short)f2bf(a1.w);
    *(bf16x8*)(xb + e) = o;
  }
}

// ---- generic fp32 -> bf16 (weights)
__global__ void k_cvt_w(const float* __restrict__ w, unsigned short* __restrict__ wb, int n8) {
  int i = blockIdx.x*blockDim.x + threadIdx.x;
  if (i >= n8) return;
  float4 a0 = ((const float4*)w)[2*i];
  float4 a1 = ((const float4*)w)[2*i+1];
  bf16x8 o;
  o[0]=(short)f2bf(a0.x); o[1]=(short)f2bf(a0.y); o[2]=(short)f2bf(a0.z); o[3]=(short)f2bf(a0.w);
  o[4]=(short)f2bf(a1.x); o[5]=(short)f2bf(a1.y); o[6]=(short)f2bf(a1.z); o[7]=(short)f2bf(a1.w);
  ((bf16x8*)wb)[i] = o;
}

// ---- 256x256 bf16 GEMM, k-slice ring, 8-phase-style counted-vmcnt schedule.
// C[m,n] = sum_k A[m,k]*B[n,k] + bias[n]
// MODE 0: write bf16 into Cb.  MODE 1: write fp32 into Cf with -SHIFT roll scatter.
// Ring: 4 slots x 32 KB (A 16K + B 16K), slice = K-width 32. Stage slice s+2
// during slice s; boundary wait = counted vmcnt(4) (drains s+1, leaves s+2).
template<int MODE>
__global__ __launch_bounds__(512, 1)
void k_gemm256(const unsigned short* __restrict__ A, const unsigned short* __restrict__ Bw,
               const float* __restrict__ bias, unsigned short* __restrict__ Cb,
               float* __restrict__ Cf, int M, int N, int K, int nTN, long long c0) {
  __shared__ char lds[4*32768];               // 128 KiB
  const int nsl = K >> 5;                     // K-slices of 32 (768 -> 24)
  int nwg = gridDim.x;                        // divisible by 8 by construction
  int cpx = nwg >> 3;
  int wg  = (blockIdx.x & 7) * cpx + (blockIdx.x >> 3);   // XCD-contiguous
  int bm = wg / nTN, bn = wg - bm*nTN;
  long long m0 = (long long)bm * 256;
  int n0 = bn * 256;
  int tid = threadIdx.x;
  int lane = tid & 63, wid = tid >> 6;
  int wr = wid >> 2, wc = wid & 3;            // 2M x 4N waves, each 128x64 of C
  int cl = lane & 15, g4 = lane >> 4;

  // staging sources: thread covers row tid>>2, 16B chunk tid&3 of each 8KB block
  const long long K2 = 2LL * K;
  const char* gA0 = (const char*)A + (m0 + (tid >> 2)) * K2 + (tid & 3) * 16;
  const char* gA1 = gA0 + 128 * K2;
  const char* gB0 = (const char*)Bw + (long long)(n0 + (tid >> 2)) * K2 + (tid & 3) * 16;
  const char* gB1 = gB0 + 128 * K2;
  int ldst = tid * 16;                        // region-local LDS dest (linear)

  // frag read offsets (region-local). A rows 64B: off = row*64 + g4*16
  int aoff = (wr * 128 + cl) * 64 + g4 * 16;           // + mf*1024
  int boff = 16384 + (wc * 64 + cl) * 64 + g4 * 16;    // + nf*1024

  f32x4 acc[8][4];
  #pragma unroll
  for (int i = 0; i < 8; ++i)
    #pragma unroll
    for (int j = 0; j < 4; ++j) acc[i][j] = (f32x4){0.f,0.f,0.f,0.f};

  // ---- prologue: stage slices 0 and 1 (4 loads each), drain slice 0
  {
    char* s0 = lds;
    char* s1 = lds + 32768;
    G2L(gA0,       s0 + ldst);
    G2L(gA1,       s0 + 8192  + ldst);
    G2L(gB0,       s0 + 16384 + ldst);
    G2L(gB1,       s0 + 24576 + ldst);
    G2L(gA0 + 64,  s1 + ldst);
    G2L(gA1 + 64,  s1 + 8192  + ldst);
    G2L(gB0 + 64,  s1 + 16384 + ldst);
    G2L(gB1 + 64,  s1 + 24576 + ldst);
    asm volatile("s_waitcnt vmcnt(4)" ::: "memory");
    __builtin_amdgcn_sched_barrier(0);
    __builtin_amdgcn_s_barrier();
  }

#define MFMA_ROW(av, m) \
    acc[m][0] = __builtin_amdgcn_mfma_f32_16x16x32_bf16(av, b0, acc[m][0], 0, 0, 0); \
    acc[m][1] = __builtin_amdgcn_mfma_f32_16x16x32_bf16(av, b1, acc[m][1], 0, 0, 0); \
    acc[m][2] = __builtin_amdgcn_mfma_f32_16x16x32_bf16(av, b2, acc[m][2], 0, 0, 0); \
    acc[m][3] = __builtin_amdgcn_mfma_f32_16x16x32_bf16(av, b3, acc[m][3], 0, 0, 0);

  for (int s = 0; s < nsl; ++s) {
    char* sb  = lds + ((s & 3) << 15);
    char* stb = lds + (((s + 2) & 3) << 15);
    long long kb2 = (long long)(s + 2) << 6;         // +64 B per slice
    bool doStage = (s + 2) < nsl;

    // ======== phase 0: A mf0-3 + B nf0-3 reads, stage A of s+2, MFMA mf0-3
    bf16x8 a0 = *(const bf16x8*)(sb + aoff);
    bf16x8 a1 = *(const bf16x8*)(sb + aoff + 1024);
    bf16x8 a2 = *(const bf16x8*)(sb + aoff + 2048);
    bf16x8 a3 = *(const bf16x8*)(sb + aoff + 3072);
    bf16x8 b0 = *(const bf16x8*)(sb + boff);
    bf16x8 b1 = *(const bf16x8*)(sb + boff + 1024);
    bf16x8 b2 = *(const bf16x8*)(sb + boff + 2048);
    bf16x8 b3 = *(const bf16x8*)(sb + boff + 3072);
    if (doStage) {
      G2L(gA0 + kb2, stb + ldst);
      G2L(gA1 + kb2, stb + 8192 + ldst);
    }
    __builtin_amdgcn_sched_barrier(0);
    __builtin_amdgcn_s_barrier();
    asm volatile("s_waitcnt lgkmcnt(0)" ::: "memory");
    __builtin_amdgcn_sched_barrier(0);
    __builtin_amdgcn_s_setprio(1);
    MFMA_ROW(a0, 0)
    MFMA_ROW(a1, 1)
    MFMA_ROW(a2, 2)
    MFMA_ROW(a3, 3)
    __builtin_amdgcn_s_setprio(0);
    __builtin_amdgcn_sched_barrier(0);
    __builtin_amdgcn_s_barrier();

    // ======== phase 1: A mf4-7 reads, stage B of s+2, boundary vmcnt, MFMA mf4-7
    bf16x8 a4 = *(const bf16x8*)(sb + aoff + 4096);
    bf16x8 a5 = *(const bf16x8*)(sb + aoff + 5120);
    bf16x8 a6 = *(const bf16x8*)(sb + aoff + 6144);
    bf16x8 a7 = *(const bf16x8*)(sb + aoff + 7168);
    if (doStage) {
      G2L(gB0 + kb2, stb + 16384 + ldst);
      G2L(gB1 + kb2, stb + 24576 + ldst);
      asm volatile("s_waitcnt vmcnt(4)" ::: "memory");   // drain s+1, keep s+2
    } else if (s + 1 < nsl) {
      asm volatile("s_waitcnt vmcnt(0)" ::: "memory");   // tail: drain last slice
    }
    __builtin_amdgcn_sched_barrier(0);
    __builtin_amdgcn_s_barrier();
    asm volatile("s_waitcnt lgkmcnt(0)" ::: "memory");
    __builtin_amdgcn_sched_barrier(0);
    __builtin_amdgcn_s_setprio(1);
    MFMA_ROW(a4, 4)
    MFMA_ROW(a5, 5)
    MFMA_ROW(a6, 6)
    MFMA_ROW(a7, 7)
    __builtin_amdgcn_s_setprio(0);
    __builtin_amdgcn_sched_barrier(0);
    __builtin_amdgcn_s_barrier();
  }
#undef MFMA_ROW

  // ---- epilogue
  #pragma unroll
  for (int mf = 0; mf < 8; ++mf) {
    #pragma unroll
    for (int nf = 0; nf < 4; ++nf) {
      int n = n0 + wc*64 + nf*16 + cl;
      float bv = bias[n];
      #pragma unroll
      for (int r = 0; r < 4; ++r) {
        long long m = m0 + wr*128 + mf*16 + g4*4 + r;
        float v = acc[mf][nf][r] + bv;
        if (MODE == 0) {
          Cb[m * (long long)N + n] = f2bf(v);
        } else {
          long long gm = c0 + m;                                     // global rolled token
          long long om = (gm & ~(long long)(SEQ-1)) | ((gm - SHIFT_T) & (long long)(SEQ-1));
          Cf[om * (long long)N + n] = v;
        }
      }
    }
  }
}

// ---- per-(window,head) attention: S = QK^T*scale + rel_bias, softmax, O = P V
__global__ __launch_bounds__(256, 4)
void k_attn(const unsigned short* __restrict__ qkv, const float* __restrict__ rel_bias,
            unsigned short* __restrict__ y) {
  int w = blockIdx.x / NHEAD;
  int h = blockIdx.x - w*NHEAD;
  __shared__ unsigned short sQ[64*72], sK[64*72], sV[64*72];
  __shared__ unsigned short sP[4][16*72];
  __shared__ float rb[128];
  int tid = threadIdx.x, lane = tid & 63, wid = tid >> 6;
  int cl = lane & 15, g4 = lane >> 4;

  if (tid < 2*WINSZ - 1) rb[tid] = rel_bias[h*(2*WINSZ-1) + tid];

  const unsigned short* base = qkv + (long long)w*WINSZ*QKV_N + h*HDIM;
  #pragma unroll
  for (int pass = 0; pass < 2; ++pass) {
    int row = (tid >> 3) + pass*32;
    int ch  = tid & 7;
    const unsigned short* src = base + (long long)row*QKV_N + ch*8;
    *(bf16x8*)(sQ + row*72 + ch*8) = *(const bf16x8*)(src);
    *(bf16x8*)(sK + row*72 + ch*8) = *(const bf16x8*)(src + DMODEL);
    *(bf16x8*)(sV + row*72 + ch*8) = *(const bf16x8*)(src + 2*DMODEL);
  }
  __syncthreads();

  // QK^T : wave wid owns q-rows [wid*16, wid*16+16)
  f32x4 sc[4];
  #pragma unroll
  for (int nt = 0; nt < 4; ++nt) sc[nt] = (f32x4){0.f,0.f,0.f,0.f};
  #pragma unroll
  for (int kk = 0; kk < 2; ++kk) {
    bf16x8 aq = *(const bf16x8*)(sQ + (wid*16 + cl)*72 + kk*32 + g4*8);
    #pragma unroll
    for (int nt = 0; nt < 4; ++nt) {
      bf16x8 bk = *(const bf16x8*)(sK + (nt*16 + cl)*72 + kk*32 + g4*8);
      sc[nt] = __builtin_amdgcn_mfma_f32_16x16x32_bf16(aq, bk, sc[nt], 0, 0, 0);
    }
  }

  // softmax over 64 cols; C layout: col = nt*16+cl, row(within wave) = g4*4 + r
  float pv[4][4];
  #pragma unroll
  for (int r = 0; r < 4; ++r) {
    int qi = wid*16 + g4*4 + r;
    float mx = -1e30f;
    #pragma unroll
    for (int nt = 0; nt < 4; ++nt) {
      int kj = nt*16 + cl;
      float v = sc[nt][r]*0.125f + rb[kj - qi + (WINSZ-1)];
      pv[nt][r] = v;
      mx = fmaxf(mx, v);
    }
    #pragma unroll
    for (int m = 1; m < 16; m <<= 1) mx = fmaxf(mx, __shfl_xor(mx, m, 64));
    float sum = 0.f;
    #pragma unroll
    for (int nt = 0; nt < 4; ++nt) { float e = __expf(pv[nt][r]-mx); pv[nt][r] = e; sum += e; }
    #pragma unroll
    for (int m = 1; m < 16; m <<= 1) sum += __shfl_xor(sum, m, 64);
    float inv = 1.f / sum;
    #pragma unroll
    for (int nt = 0; nt < 4; ++nt)
      sP[wid][(g4*4+r)*72 + nt*16 + cl] = f2bf(pv[nt][r]*inv);
  }
  // wave-local LDS RAW: compiler inserts lgkmcnt; sP[wid] is wave-private

  // O = P @ V
  f32x4 o[4];
  #pragma unroll
  for (int nt = 0; nt < 4; ++nt) o[nt] = (f32x4){0.f,0.f,0.f,0.f};
  #pragma unroll
  for (int kk = 0; kk < 2; ++kk) {
    bf16x8 ap = *(const bf16x8*)(&sP[wid][cl*72 + kk*32 + g4*8]);
    #pragma unroll
    for (int nt = 0; nt < 4; ++nt) {
      bf16x8 bv;
      #pragma unroll
      for (int j = 0; j < 8; ++j)
        bv[j] = (short)sV[(kk*32 + g4*8 + j)*72 + nt*16 + cl];   // column gather of V
      o[nt] = __builtin_amdgcn_mfma_f32_16x16x32_bf16(ap, bv, o[nt], 0, 0, 0);
    }
  }

  long long tokbase = (long long)w * WINSZ;
  #pragma unroll
  for (int nt = 0; nt < 4; ++nt)
    #pragma unroll
    for (int r = 0; r < 4; ++r) {
      int row = wid*16 + g4*4 + r;
      y[(tokbase + row) * (long long)DMODEL + h*HDIM + nt*16 + cl] = f2bf(o[nt][r]);
    }
}

extern "C" void kernel_launch(void* const* d_in, const int* in_sizes, int n_in,
                              void* d_out, int out_size, void* d_ws, size_t ws_size,
                              hipStream_t stream) {
  const float* x      = (const float*)d_in[0];
  const float* qkv_w  = (const float*)d_in[1];
  const float* qkv_b  = (const float*)d_in[2];
  const float* proj_w = (const float*)d_in[3];
  const float* proj_b = (const float*)d_in[4];
  const float* rel_b  = (const float*)d_in[5];
  float* out = (float*)d_out;

  const long long NTOK = (long long)NBATCH * SEQ;    // 65536
  const size_t wbytes = (size_t)QKV_N*DMODEL*2 + (size_t)DMODEL*DMODEL*2;  // 4,718,592

  // pick chunk count: smallest C in {1,2,4,8,16} whose working set fits ws
  int C = 16;
  for (int c : {1, 2, 4, 8, 16}) {
    size_t tpc = (size_t)NTOK / c;
    size_t need = tpc*QKV_N*2 + tpc*DMODEL*2 + wbytes;
    if (need <= ws_size) { C = c; break; }
  }
  long long tpc = NTOK / C;

  char* ws = (char*)d_ws;
  unsigned short* qkvb = (unsigned short*)ws;                               // tpc*2304 bf16
  unsigned short* xb   = (unsigned short*)(ws + (size_t)tpc*QKV_N*2);       // tpc*768 bf16 (aliased as y)
  unsigned short* wq   = (unsigned short*)(ws + (size_t)tpc*QKV_N*2 + (size_t)tpc*DMODEL*2);
  unsigned short* wp   = wq + (size_t)QKV_N*DMODEL;

  k_cvt_w<<<(QKV_N*DMODEL/8 + 255)/256, 256, 0, stream>>>(qkv_w, wq, QKV_N*DMODEL/8);
  k_cvt_w<<<(DMODEL*DMODEL/8 + 255)/256, 256, 0, stream>>>(proj_w, wp, DMODEL*DMODEL/8);

  for (int c = 0; c < C; ++c) {
    long long c0 = (long long)c * tpc;
    long long n8 = tpc * DMODEL / 8;
    int cvtGrid = (int)((n8 + 255) / 256); if (cvtGrid > 2048) cvtGrid = 2048;
    k_cvt_x<<<cvtGrid, 256, 0, stream>>>(x, xb, c0, n8);

    int mT = (int)(tpc / 256);
    k_gemm256<0><<<mT * (QKV_N/256), 512, 0, stream>>>(xb, wq, qkv_b, qkvb, nullptr,
                                                       (int)tpc, QKV_N, DMODEL, QKV_N/256, c0);
    k_attn<<<(int)(tpc/WINSZ) * NHEAD, 256, 0, stream>>>(qkvb, rel_b, xb /*reuse as y*/);
    k_gemm256<1><<<mT * (DMODEL/256), 512, 0, stream>>>(xb, wp, proj_b, nullptr, out,
                                                        (int)tpc, DMODEL, DMODEL, DMODEL/256, c0);
  }
}

// Round 3
// 525.675 us; speedup vs baseline: 1.0651x; 1.0165x over previous
//
#include <hip/hip_runtime.h>
#include <hip/hip_bf16.h>
#include <stdint.h>

#define SEQ     4096
#define NBATCH  16
#define DMODEL  768
#define NHEAD   12
#define HDIM    64
#define WINSZ   64
#define SHIFT_T 32
#define QKV_N   (3*DMODEL)   // 2304

typedef __attribute__((ext_vector_type(8))) short  bf16x8;
typedef __attribute__((ext_vector_type(4))) float  f32x4;

static __device__ __forceinline__ unsigned short f2bf(float f) {
  union { float f; unsigned u; } v; v.f = f;
  unsigned r = v.u + 0x7fffu + ((v.u >> 16) & 1u);
  return (unsigned short)(r >> 16);
}

#define G2L(gp, lp) __builtin_amdgcn_global_load_lds( \
    (const __attribute__((address_space(1))) unsigned*)(const void*)(gp), \
    (__attribute__((address_space(3))) unsigned*)(void*)(lp), 16, 0, 0)

// ---- cast x (fp32) -> bf16 with +SHIFT roll fused; chunked by token base c0
__global__ void k_cvt_x(const float* __restrict__ x, unsigned short* __restrict__ xb,
                        long long c0, long long n8) {
  for (long long i = (long long)blockIdx.x*blockDim.x + threadIdx.x; i < n8;
       i += (long long)gridDim.x*blockDim.x) {
    long long e = i*8;
    int d = (int)(e % DMODEL);
    long long gt = c0 + e / DMODEL;          // global rolled token index
    int t = (int)(gt & (SEQ-1));
    long long b = gt >> 12;
    int ts = (t - SHIFT_T) & (SEQ-1);        // source (unrolled) position
    const float* src = x + (((b << 12) + ts) * (long long)DMODEL + d);
    float4 a0 = *(const float4*)src;
    float4 a1 = *(const float4*)(src + 4);
    bf16x8 o;
    o[0]=(short)f2bf(a0.x); o[1]=(short)f2bf(a0.y); o[2]=(short)f2bf(a0.z); o[3]=(short)f2bf(a0.w);
    o[4]=(short)f2bf(a1.x); o[5]=(short)f2bf(a1.y); o[6]=(short)f2bf(a1.z); o[7]=(short)f2bf(a1.w);
    *(bf16x8*)(xb + e) = o;
  }
}

// ---- generic fp32 -> bf16 (weights)
__global__ void k_cvt_w(const float* __restrict__ w, unsigned short* __restrict__ wb, int n8) {
  int i = blockIdx.x*blockDim.x + threadIdx.x;
  if (i >= n8) return;
  float4 a0 = ((const float4*)w)[2*i];
  float4 a1 = ((const float4*)w)[2*i+1];
  bf16x8 o;
  o[0]=(short)f2bf(a0.x); o[1]=(short)f2bf(a0.y); o[2]=(short)f2bf(a0.z); o[3]=(short)f2bf(a0.w);
  o[4]=(short)f2bf(a1.x); o[5]=(short)f2bf(a1.y); o[6]=(short)f2bf(a1.z); o[7]=(short)f2bf(a1.w);
  ((bf16x8*)wb)[i] = o;
}

// ---- 256x256 bf16 GEMM, k-slice ring, counted-vmcnt schedule + T2 swizzle.
// C[m,n] = sum_k A[m,k]*B[n,k] + bias[n]
// MODE 0: write bf16 into Cb.  MODE 1: write fp32 into Cf with -SHIFT roll scatter.
// Ring: 4 slots x 32 KB (A 16K + B 16K), slice = K-width 32 (64 B rows).
// Swizzle (per 8 KiB region, involution): P ^= ((P>>7)&7)<<4  — LDS dest stays
// LINEAR for global_load_lds; the global SOURCE is inverse-permuted; ds_reads
// XOR their base with (cl>>1)<<4 (constant per lane). 2 lanes/bank => free.
template<int MODE>
__global__ __launch_bounds__(512, 1)
void k_gemm256(const unsigned short* __restrict__ A, const unsigned short* __restrict__ Bw,
               const float* __restrict__ bias, unsigned short* __restrict__ Cb,
               float* __restrict__ Cf, int M, int N, int K, int nTN, long long c0) {
  __shared__ char lds[4*32768];               // 128 KiB
  const int nsl = K >> 5;                     // K-slices of 32 (768 -> 24)
  int nwg = gridDim.x;                        // divisible by 8 by construction
  int cpx = nwg >> 3;
  int wg  = (blockIdx.x & 7) * cpx + (blockIdx.x >> 3);   // XCD-contiguous
  int bm = wg / nTN, bn = wg - bm*nTN;
  long long m0 = (long long)bm * 256;
  int n0 = bn * 256;
  int tid = threadIdx.x;
  int lane = tid & 63, wid = tid >> 6;
  int wr = wid >> 2, wc = wid & 3;            // 2M x 4N waves, each 128x64 of C
  int cl = lane & 15, g4 = lane >> 4;

  // staging: thread tid fills LINEAR LDS bytes [tid*16, tid*16+16) of each 8KB
  // region; global source is the inverse-swizzled logical location.
  const long long K2 = 2LL * K;
  int L  = tid * 16;
  int Ls = L ^ (((L >> 7) & 7) << 4);         // involution
  int srow = Ls >> 6;                         // logical row 0..127
  int scol = Ls & 63;                         // byte within 64B row window
  const char* gA0 = (const char*)A + (m0 + srow) * K2 + scol;
  const char* gA1 = (const char*)A + (m0 + 128 + srow) * K2 + scol;
  const char* gB0 = (const char*)Bw + (long long)(n0 + srow) * K2 + scol;
  const char* gB1 = (const char*)Bw + (long long)(n0 + 128 + srow) * K2 + scol;
  int ldst = L;                               // linear LDS dest

  // swizzled frag-read base offsets (mf*1024 / nf*1024 preserve the XOR bits)
  int aoff = (wr*8192 + cl*64 + g4*16) ^ ((cl >> 1) << 4);
  int boff = (16384 + wc*4096 + cl*64 + g4*16) ^ ((cl >> 1) << 4);

  f32x4 acc[8][4];
  #pragma unroll
  for (int i = 0; i < 8; ++i)
    #pragma unroll
    for (int j = 0; j < 4; ++j) acc[i][j] = (f32x4){0.f,0.f,0.f,0.f};

  // ---- prologue: stage slices 0 and 1 (4 loads each), drain slice 0
  {
    char* s0 = lds;
    char* s1 = lds + 32768;
    G2L(gA0,       s0 + ldst);
    G2L(gA1,       s0 + 8192  + ldst);
    G2L(gB0,       s0 + 16384 + ldst);
    G2L(gB1,       s0 + 24576 + ldst);
    G2L(gA0 + 64,  s1 + ldst);
    G2L(gA1 + 64,  s1 + 8192  + ldst);
    G2L(gB0 + 64,  s1 + 16384 + ldst);
    G2L(gB1 + 64,  s1 + 24576 + ldst);
    asm volatile("s_waitcnt vmcnt(4)" ::: "memory");
    __builtin_amdgcn_sched_barrier(0);
    __builtin_amdgcn_s_barrier();
  }

#define MFMA_ROW(av, m) \
    acc[m][0] = __builtin_amdgcn_mfma_f32_16x16x32_bf16(av, b0, acc[m][0], 0, 0, 0); \
    acc[m][1] = __builtin_amdgcn_mfma_f32_16x16x32_bf16(av, b1, acc[m][1], 0, 0, 0); \
    acc[m][2] = __builtin_amdgcn_mfma_f32_16x16x32_bf16(av, b2, acc[m][2], 0, 0, 0); \
    acc[m][3] = __builtin_amdgcn_mfma_f32_16x16x32_bf16(av, b3, acc[m][3], 0, 0, 0);

  for (int s = 0; s < nsl; ++s) {
    char* sb  = lds + ((s & 3) << 15);
    char* stb = lds + (((s + 2) & 3) << 15);
    long long kb2 = (long long)(s + 2) << 6;         // +64 B per slice
    bool doStage = (s + 2) < nsl;

    // ======== phase 0: A mf0-3 + B nf0-3 reads, stage A of s+2, MFMA mf0-3
    bf16x8 a0 = *(const bf16x8*)(sb + aoff);
    bf16x8 a1 = *(const bf16x8*)(sb + aoff + 1024);
    bf16x8 a2 = *(const bf16x8*)(sb + aoff + 2048);
    bf16x8 a3 = *(const bf16x8*)(sb + aoff + 3072);
    bf16x8 b0 = *(const bf16x8*)(sb + boff);
    bf16x8 b1 = *(const bf16x8*)(sb + boff + 1024);
    bf16x8 b2 = *(const bf16x8*)(sb + boff + 2048);
    bf16x8 b3 = *(const bf16x8*)(sb + boff + 3072);
    if (doStage) {
      G2L(gA0 + kb2, stb + ldst);
      G2L(gA1 + kb2, stb + 8192 + ldst);
    }
    __builtin_amdgcn_sched_barrier(0);
    __builtin_amdgcn_s_barrier();
    asm volatile("s_waitcnt lgkmcnt(0)" ::: "memory");
    __builtin_amdgcn_sched_barrier(0);
    __builtin_amdgcn_s_setprio(1);
    MFMA_ROW(a0, 0)
    MFMA_ROW(a1, 1)
    MFMA_ROW(a2, 2)
    MFMA_ROW(a3, 3)
    __builtin_amdgcn_s_setprio(0);
    __builtin_amdgcn_sched_barrier(0);
    __builtin_amdgcn_s_barrier();

    // ======== phase 1: A mf4-7 reads, stage B of s+2, boundary vmcnt, MFMA mf4-7
    bf16x8 a4 = *(const bf16x8*)(sb + aoff + 4096);
    bf16x8 a5 = *(const bf16x8*)(sb + aoff + 5120);
    bf16x8 a6 = *(const bf16x8*)(sb + aoff + 6144);
    bf16x8 a7 = *(const bf16x8*)(sb + aoff + 7168);
    if (doStage) {
      G2L(gB0 + kb2, stb + 16384 + ldst);
      G2L(gB1 + kb2, stb + 24576 + ldst);
      asm volatile("s_waitcnt vmcnt(4)" ::: "memory");   // drain s+1, keep s+2
    } else if (s + 1 < nsl) {
      asm volatile("s_waitcnt vmcnt(0)" ::: "memory");   // tail: drain last slice
    }
    __builtin_amdgcn_sched_barrier(0);
    __builtin_amdgcn_s_barrier();
    asm volatile("s_waitcnt lgkmcnt(0)" ::: "memory");
    __builtin_amdgcn_sched_barrier(0);
    __builtin_amdgcn_s_setprio(1);
    MFMA_ROW(a4, 4)
    MFMA_ROW(a5, 5)
    MFMA_ROW(a6, 6)
    MFMA_ROW(a7, 7)
    __builtin_amdgcn_s_setprio(0);
    __builtin_amdgcn_sched_barrier(0);
    __builtin_amdgcn_s_barrier();
  }
#undef MFMA_ROW

  // ---- epilogue
  #pragma unroll
  for (int mf = 0; mf < 8; ++mf) {
    #pragma unroll
    for (int nf = 0; nf < 4; ++nf) {
      int n = n0 + wc*64 + nf*16 + cl;
      float bv = bias[n];
      #pragma unroll
      for (int r = 0; r < 4; ++r) {
        long long m = m0 + wr*128 + mf*16 + g4*4 + r;
        float v = acc[mf][nf][r] + bv;
        if (MODE == 0) {
          Cb[m * (long long)N + n] = f2bf(v);
        } else {
          long long gm = c0 + m;                                     // global rolled token
          long long om = (gm & ~(long long)(SEQ-1)) | ((gm - SHIFT_T) & (long long)(SEQ-1));
          Cf[om * (long long)N + n] = v;
        }
      }
    }
  }
}

// ---- per-(window,head) attention: S = QK^T*scale + rel_bias, softmax, O = P V
__global__ __launch_bounds__(256, 4)
void k_attn(const unsigned short* __restrict__ qkv, const float* __restrict__ rel_bias,
            unsigned short* __restrict__ y) {
  int w = blockIdx.x / NHEAD;
  int h = blockIdx.x - w*NHEAD;
  __shared__ unsigned short sQ[64*72], sK[64*72], sV[64*72];
  __shared__ unsigned short sP[4][16*72];
  __shared__ float rb[128];
  int tid = threadIdx.x, lane = tid & 63, wid = tid >> 6;
  int cl = lane & 15, g4 = lane >> 4;

  if (tid < 2*WINSZ - 1) rb[tid] = rel_bias[h*(2*WINSZ-1) + tid];

  const unsigned short* base = qkv + (long long)w*WINSZ*QKV_N + h*HDIM;
  #pragma unroll
  for (int pass = 0; pass < 2; ++pass) {
    int row = (tid >> 3) + pass*32;
    int ch  = tid & 7;
    const unsigned short* src = base + (long long)row*QKV_N + ch*8;
    *(bf16x8*)(sQ + row*72 + ch*8) = *(const bf16x8*)(src);
    *(bf16x8*)(sK + row*72 + ch*8) = *(const bf16x8*)(src + DMODEL);
    *(bf16x8*)(sV + row*72 + ch*8) = *(const bf16x8*)(src + 2*DMODEL);
  }
  __syncthreads();

  // QK^T : wave wid owns q-rows [wid*16, wid*16+16)
  f32x4 sc[4];
  #pragma unroll
  for (int nt = 0; nt < 4; ++nt) sc[nt] = (f32x4){0.f,0.f,0.f,0.f};
  #pragma unroll
  for (int kk = 0; kk < 2; ++kk) {
    bf16x8 aq = *(const bf16x8*)(sQ + (wid*16 + cl)*72 + kk*32 + g4*8);
    #pragma unroll
    for (int nt = 0; nt < 4; ++nt) {
      bf16x8 bk = *(const bf16x8*)(sK + (nt*16 + cl)*72 + kk*32 + g4*8);
      sc[nt] = __builtin_amdgcn_mfma_f32_16x16x32_bf16(aq, bk, sc[nt], 0, 0, 0);
    }
  }

  // softmax over 64 cols; C layout: col = nt*16+cl, row(within wave) = g4*4 + r
  float pv[4][4];
  #pragma unroll
  for (int r = 0; r < 4; ++r) {
    int qi = wid*16 + g4*4 + r;
    float mx = -1e30f;
    #pragma unroll
    for (int nt = 0; nt < 4; ++nt) {
      int kj = nt*16 + cl;
      float v = sc[nt][r]*0.125f + rb[kj - qi + (WINSZ-1)];
      pv[nt][r] = v;
      mx = fmaxf(mx, v);
    }
    #pragma unroll
    for (int m = 1; m < 16; m <<= 1) mx = fmaxf(mx, __shfl_xor(mx, m, 64));
    float sum = 0.f;
    #pragma unroll
    for (int nt = 0; nt < 4; ++nt) { float e = __expf(pv[nt][r]-mx); pv[nt][r] = e; sum += e; }
    #pragma unroll
    for (int m = 1; m < 16; m <<= 1) sum += __shfl_xor(sum, m, 64);
    float inv = 1.f / sum;
    #pragma unroll
    for (int nt = 0; nt < 4; ++nt)
      sP[wid][(g4*4+r)*72 + nt*16 + cl] = f2bf(pv[nt][r]*inv);
  }
  // wave-local LDS RAW: compiler inserts lgkmcnt; sP[wid] is wave-private

  // O = P @ V
  f32x4 o[4];
  #pragma unroll
  for (int nt = 0; nt < 4; ++nt) o[nt] = (f32x4){0.f,0.f,0.f,0.f};
  #pragma unroll
  for (int kk = 0; kk < 2; ++kk) {
    bf16x8 ap = *(const bf16x8*)(&sP[wid][cl*72 + kk*32 + g4*8]);
    #pragma unroll
    for (int nt = 0; nt < 4; ++nt) {
      bf16x8 bv;
      #pragma unroll
      for (int j = 0; j < 8; ++j)
        bv[j] = (short)sV[(kk*32 + g4*8 + j)*72 + nt*16 + cl];   // column gather of V
      o[nt] = __builtin_amdgcn_mfma_f32_16x16x32_bf16(ap, bv, o[nt], 0, 0, 0);
    }
  }

  long long tokbase = (long long)w * WINSZ;
  #pragma unroll
  for (int nt = 0; nt < 4; ++nt)
    #pragma unroll
    for (int r = 0; r < 4; ++r) {
      int row = wid*16 + g4*4 + r;
      y[(tokbase + row) * (long long)DMODEL + h*HDIM + nt*16 + cl] = f2bf(o[nt][r]);
    }
}

extern "C" void kernel_launch(void* const* d_in, const int* in_sizes, int n_in,
                              void* d_out, int out_size, void* d_ws, size_t ws_size,
                              hipStream_t stream) {
  const float* x      = (const float*)d_in[0];
  const float* qkv_w  = (const float*)d_in[1];
  const float* qkv_b  = (const float*)d_in[2];
  const float* proj_w = (const float*)d_in[3];
  const float* proj_b = (const float*)d_in[4];
  const float* rel_b  = (const float*)d_in[5];
  float* out = (float*)d_out;

  const long long NTOK = (long long)NBATCH * SEQ;    // 65536
  const size_t wbytes = (size_t)QKV_N*DMODEL*2 + (size_t)DMODEL*DMODEL*2;  // 4,718,592

  // pick chunk count: smallest C in {1,2,4,8,16} whose working set fits ws
  int C = 16;
  for (int c : {1, 2, 4, 8, 16}) {
    size_t tpc = (size_t)NTOK / c;
    size_t need = tpc*QKV_N*2 + tpc*DMODEL*2 + wbytes;
    if (need <= ws_size) { C = c; break; }
  }
  long long tpc = NTOK / C;

  char* ws = (char*)d_ws;
  unsigned short* qkvb = (unsigned short*)ws;                               // tpc*2304 bf16
  unsigned short* xb   = (unsigned short*)(ws + (size_t)tpc*QKV_N*2);       // tpc*768 bf16 (aliased as y)
  unsigned short* wq   = (unsigned short*)(ws + (size_t)tpc*QKV_N*2 + (size_t)tpc*DMODEL*2);
  unsigned short* wp   = wq + (size_t)QKV_N*DMODEL;

  k_cvt_w<<<(QKV_N*DMODEL/8 + 255)/256, 256, 0, stream>>>(qkv_w, wq, QKV_N*DMODEL/8);
  k_cvt_w<<<(DMODEL*DMODEL/8 + 255)/256, 256, 0, stream>>>(proj_w, wp, DMODEL*DMODEL/8);

  for (int c = 0; c < C; ++c) {
    long long c0 = (long long)c * tpc;
    long long n8 = tpc * DMODEL / 8;
    int cvtGrid = (int)((n8 + 255) / 256); if (cvtGrid > 2048) cvtGrid = 2048;
    k_cvt_x<<<cvtGrid, 256, 0, stream>>>(x, xb, c0, n8);

    int mT = (int)(tpc / 256);
    k_gemm256<0><<<mT * (QKV_N/256), 512, 0, stream>>>(xb, wq, qkv_b, qkvb, nullptr,
                                                       (int)tpc, QKV_N, DMODEL, QKV_N/256, c0);
    k_attn<<<(int)(tpc/WINSZ) * NHEAD, 256, 0, stream>>>(qkvb, rel_b, xb /*reuse as y*/);
    k_gemm256<1><<<mT * (DMODEL/256), 512, 0, stream>>>(xb, wp, proj_b, nullptr, out,
                                                        (int)tpc, DMODEL, DMODEL, DMODEL/256, c0);
  }
}